// Round 11
// baseline (118.033 us; speedup 1.0000x reference)
//
#include <hip/hip_runtime.h>
#include <hip/hip_bf16.h>

typedef short bf16x8 __attribute__((ext_vector_type(8)));
typedef float f32x4  __attribute__((ext_vector_type(4)));

typedef __attribute__((address_space(3))) void lds_t;
typedef __attribute__((address_space(1))) void gbl_t;

#define MFMA16(a,b,c) __builtin_amdgcn_mfma_f32_16x16x32_bf16((a),(b),(c),0,0,0)

__device__ __forceinline__ unsigned short f2bf(float f) {
    __hip_bfloat16 h = __float2bfloat16(f);
    return __builtin_bit_cast(unsigned short, h);
}
__device__ __forceinline__ float bf2f(unsigned short u) {
    __hip_bfloat16 h = __builtin_bit_cast(__hip_bfloat16, u);
    return __bfloat162float(h);
}

// f32 [R][1024] -> bf16 hi-only compact [R][1024].  float4 vectorized.
__global__ void prep_hi_rows(const float* __restrict__ src,
                             unsigned short* __restrict__ dst, int total4) {
    for (int idx = blockIdx.x * blockDim.x + threadIdx.x; idx < total4;
         idx += gridDim.x * blockDim.x) {
        int base = idx * 4;
        float4 v = *reinterpret_cast<const float4*>(src + base);
        ushort4 hi;
        hi.x = f2bf(v.x);
        hi.y = f2bf(v.y);
        hi.z = f2bf(v.z);
        hi.w = f2bf(v.w);
        *reinterpret_cast<ushort4*>(dst + base) = hi;
    }
}

// w_qkv [3072][1024], einops row permute (out row n = which*1024+h*64+d reads
// src row d*48+which*16+h) -> bf16 hi-only compact [3072][1024].
__global__ void prep_hi_wqkv(const float* __restrict__ w,
                             unsigned short* __restrict__ dst) {
    for (int idx = blockIdx.x * blockDim.x + threadIdx.x; idx < 3072 * 256;
         idx += gridDim.x * blockDim.x) {
        int base = idx * 4;
        int n = base >> 10, c = base & 1023;
        int d = n & 63, which = n >> 10, h = (n >> 6) & 15;
        int srow = d * 48 + which * 16 + h;
        float4 v = *reinterpret_cast<const float4*>(w + (size_t)srow * 1024 + c);
        ushort4 hi;
        hi.x = f2bf(v.x);
        hi.y = f2bf(v.y);
        hi.z = f2bf(v.z);
        hi.w = f2bf(v.w);
        *reinterpret_cast<ushort4*>(dst + (size_t)n * 1024 + c) = hi;
    }
}

// ============================================================================
// QKV GEMM v2 (R11): hi-only bf16, K=1024 (32 steps of BK=32).
// Tile 128(M)x256(N) -> grid (12,32) = 384 blocks = 1.5 blocks/CU: full CU
// coverage (R10 post-mortem: 192 blocks left 64 CUs idle) and 2 co-resident
// blocks on half the CUs to interleave barriers (R7 regime).
// 8 waves (2M x 4N), wave tile 64x64, acc[4][4].  3-slot LDS ring, 24KB/slot
// (A 8KB + B 16KB) = 72KB <= 80KB for 2 blocks/CU; stage slot s+2 into the
// slot freed at the s-1 barrier; counted vmcnt(3) (T4).  Chunk-XOR swizzle
// both-sides (0 conflicts).  Epilogue scatters Q,K as [bh][t][64] and V
// DIRECTLY TRANSPOSED into Vtg [bh][64][1024] (replaces transpose_v kernel).
// ============================================================================
__global__ __launch_bounds__(512, 4) void gemm256_hi(
    const unsigned short* __restrict__ A, const unsigned short* __restrict__ B,
    unsigned short* __restrict__ outQ, unsigned short* __restrict__ outK,
    unsigned short* __restrict__ outVt) {
    __shared__ unsigned short lds[3 * 12288];  // slot: A [0,4096) + B [4096,12288)
    const int tid = threadIdx.x;
    const int wid = tid >> 6, lane = tid & 63;
    const int lrow = lane & 15, lgrp = lane >> 4;
    const int wr = wid >> 2, wc = wid & 3;
    const int mtile = blockIdx.y * 128, ntile = blockIdx.x * 256;

    const int csw = lgrp ^ ((lrow >> 1) & 3);
    const int aoff = (wr * 64 + lrow) * 32 + csw * 8;         // + i*512, + slot*12288
    const int boff = 4096 + (wc * 64 + lrow) * 32 + csw * 8;  // + j*512, + slot*12288

    const int srow = tid >> 2;                        // 0..127
    const int schunk = (tid & 3) ^ ((tid >> 3) & 3);  // inverse-swizzled src
    const unsigned short* Arow = A + (size_t)(mtile + srow) * 1024 + schunk * 8;
    const unsigned short* Brow0 = B + (size_t)(ntile + srow) * 1024 + schunk * 8;
    const unsigned short* Brow1 =
        B + (size_t)(ntile + 128 + srow) * 1024 + schunk * 8;

    f32x4 acc[4][4];
#pragma unroll
    for (int i = 0; i < 4; ++i)
#pragma unroll
        for (int j = 0; j < 4; ++j) {
            f32x4 z = {0.f, 0.f, 0.f, 0.f};
            acc[i][j] = z;
        }

    // prologue: stage steps 0,1 into slots 0,1
#pragma unroll
    for (int s0 = 0; s0 < 2; ++s0) {
        const int kb = s0 * 32;
        __builtin_amdgcn_global_load_lds((const gbl_t*)(Arow + kb),
                                         (lds_t*)(lds + s0 * 12288 + tid * 8),
                                         16, 0, 0);
        __builtin_amdgcn_global_load_lds(
            (const gbl_t*)(Brow0 + kb),
            (lds_t*)(lds + s0 * 12288 + 4096 + tid * 8), 16, 0, 0);
        __builtin_amdgcn_global_load_lds(
            (const gbl_t*)(Brow1 + kb),
            (lds_t*)(lds + s0 * 12288 + 8192 + tid * 8), 16, 0, 0);
    }
    asm volatile("s_waitcnt vmcnt(3)" ::: "memory");  // slot 0 landed
    __syncthreads();

    int sa = 0;
    for (int s = 0; s < 32; ++s) {
        const unsigned short* sbase = lds + sa * 12288;

        bf16x8 af[4], bfv[4];
#pragma unroll
        for (int i = 0; i < 4; ++i)
            af[i] = *reinterpret_cast<const bf16x8*>(sbase + aoff + i * 512);
#pragma unroll
        for (int j = 0; j < 4; ++j)
            bfv[j] = *reinterpret_cast<const bf16x8*>(sbase + boff + j * 512);

        // stage slot s+2 into the slot freed at the end of step s-1
        if (s <= 29) {
            int s2 = sa + 2;
            if (s2 >= 3) s2 -= 3;
            const int kb = (s + 2) * 32;
            __builtin_amdgcn_global_load_lds(
                (const gbl_t*)(Arow + kb), (lds_t*)(lds + s2 * 12288 + tid * 8),
                16, 0, 0);
            __builtin_amdgcn_global_load_lds(
                (const gbl_t*)(Brow0 + kb),
                (lds_t*)(lds + s2 * 12288 + 4096 + tid * 8), 16, 0, 0);
            __builtin_amdgcn_global_load_lds(
                (const gbl_t*)(Brow1 + kb),
                (lds_t*)(lds + s2 * 12288 + 8192 + tid * 8), 16, 0, 0);
        }
        __builtin_amdgcn_s_setprio(1);
#pragma unroll
        for (int i = 0; i < 4; ++i)
#pragma unroll
            for (int j = 0; j < 4; ++j)
                acc[i][j] = MFMA16(af[i], bfv[j], acc[i][j]);
        __builtin_amdgcn_s_setprio(0);

        // counted wait: slot s+1's 3 loads (issued at s-1) landed; this step's
        // 3 stay in flight (T4: never 0 mid-loop).
        if (s < 31) {
            if (s <= 29)
                asm volatile("s_waitcnt vmcnt(3)" ::: "memory");
            else
                asm volatile("s_waitcnt vmcnt(0)" ::: "memory");
            __syncthreads();
        }
        sa = (sa + 1 == 3) ? 0 : sa + 1;
    }

    // epilogue: Q,K -> [bh][t][64]; V -> TRANSPOSED [bh][64][1024]
#pragma unroll
    for (int i = 0; i < 4; ++i) {
#pragma unroll
        for (int j = 0; j < 4; ++j) {
#pragma unroll
            for (int r = 0; r < 4; ++r) {
                float v = acc[i][j][r];
                int m = mtile + wr * 64 + i * 16 + lgrp * 4 + r;
                int n = ntile + wc * 64 + j * 16 + lrow;
                int which = n >> 10;
                int hh = (n >> 6) & 15;
                int d = n & 63;
                int b = m >> 10, t = m & 1023;
                if (which == 2) {
                    outVt[((size_t)((b << 4) + hh) * 64 + d) * 1024 + t] =
                        f2bf(v);
                } else {
                    unsigned short* dstp = (which == 0) ? outQ : outK;
                    dstp[((size_t)((b << 4) + hh) * 1024 + t) * 64 + d] =
                        f2bf(v);
                }
            }
        }
    }
}

// ============================================================================
// Out-projection GEMM v4 (R9, unchanged): hi-only bf16, K=1024, 64x128 tile,
// 512 blocks, 4-slot ring, counted vmcnt(3), XCD swizzle, 0 conflicts.
// ============================================================================
__global__ __launch_bounds__(256, 3) void gemm_out_v4(
    const unsigned short* __restrict__ A, const unsigned short* __restrict__ B,
    float* __restrict__ outF) {
    __shared__ unsigned short As[4][64 * 32];   // 16 KB ring
    __shared__ unsigned short Bs[4][128 * 32];  // 32 KB ring
    const int tid = threadIdx.x;
    const int wid = tid >> 6, lane = tid & 63;
    const int lrow = lane & 15, lgrp = lane >> 4;
    const int wr = wid >> 1, wc = wid & 1;
    const int h = blockIdx.x;
    const int xcd = h & 7, within = h >> 3;
    const int mtile = (xcd * 8 + (within & 7)) * 64;
    const int ntile = (within >> 3) * 128;

    const int csw = lgrp ^ ((lrow >> 1) & 3);
    const int aoff = (wr * 32 + lrow) * 32 + csw * 8;  // + i*512
    const int boff = (wc * 64 + lrow) * 32 + csw * 8;  // + j*512

    const int srow = tid >> 2;                        // 0..63
    const int schunk = (tid & 3) ^ ((tid >> 3) & 3);  // inverse-swizzled src
    const unsigned short* Arow = A + (size_t)(mtile + srow) * 1024 + schunk * 8;
    const unsigned short* Brow0 = B + (size_t)(ntile + srow) * 1024 + schunk * 8;
    const unsigned short* Brow1 =
        B + (size_t)(ntile + 64 + srow) * 1024 + schunk * 8;

    f32x4 acc[2][4];
#pragma unroll
    for (int i = 0; i < 2; ++i)
#pragma unroll
        for (int j = 0; j < 4; ++j) {
            f32x4 z = {0.f, 0.f, 0.f, 0.f};
            acc[i][j] = z;
        }

#pragma unroll
    for (int s0 = 0; s0 < 2; ++s0) {
        const int kb = s0 * 32;
        __builtin_amdgcn_global_load_lds((const gbl_t*)(Arow + kb),
                                         (lds_t*)(&As[s0][0] + tid * 8), 16, 0,
                                         0);
        __builtin_amdgcn_global_load_lds((const gbl_t*)(Brow0 + kb),
                                         (lds_t*)(&Bs[s0][0] + tid * 8), 16, 0,
                                         0);
        __builtin_amdgcn_global_load_lds((const gbl_t*)(Brow1 + kb),
                                         (lds_t*)(&Bs[s0][0] + 2048 + tid * 8),
                                         16, 0, 0);
    }
    asm volatile("s_waitcnt vmcnt(3)" ::: "memory");  // slot 0 landed
    __syncthreads();

    for (int s = 0; s < 32; ++s) {
        const int sa = s & 3;
        if (s <= 29) {
            const int kb = (s + 2) * 32;
            const int s2 = (s + 2) & 3;
            __builtin_amdgcn_global_load_lds((const gbl_t*)(Arow + kb),
                                             (lds_t*)(&As[s2][0] + tid * 8), 16,
                                             0, 0);
            __builtin_amdgcn_global_load_lds((const gbl_t*)(Brow0 + kb),
                                             (lds_t*)(&Bs[s2][0] + tid * 8), 16,
                                             0, 0);
            __builtin_amdgcn_global_load_lds(
                (const gbl_t*)(Brow1 + kb),
                (lds_t*)(&Bs[s2][0] + 2048 + tid * 8), 16, 0, 0);
        }
        bf16x8 af[2], bfv[4];
#pragma unroll
        for (int i = 0; i < 2; ++i)
            af[i] = *reinterpret_cast<const bf16x8*>(&As[sa][0] + aoff + i * 512);
#pragma unroll
        for (int j = 0; j < 4; ++j)
            bfv[j] =
                *reinterpret_cast<const bf16x8*>(&Bs[sa][0] + boff + j * 512);
        __builtin_amdgcn_s_setprio(1);
#pragma unroll
        for (int i = 0; i < 2; ++i)
#pragma unroll
            for (int j = 0; j < 4; ++j)
                acc[i][j] = MFMA16(af[i], bfv[j], acc[i][j]);
        __builtin_amdgcn_s_setprio(0);
        if (s < 31) {
            if (s <= 29)
                asm volatile("s_waitcnt vmcnt(3)" ::: "memory");
            else
                asm volatile("s_waitcnt vmcnt(0)" ::: "memory");
            __syncthreads();
        }
    }

#pragma unroll
    for (int i = 0; i < 2; ++i)
#pragma unroll
        for (int j = 0; j < 4; ++j)
#pragma unroll
            for (int r = 0; r < 4; ++r) {
                int m = mtile + wr * 32 + i * 16 + lgrp * 4 + r;
                int n = ntile + wc * 64 + j * 16 + lrow;
                outF[(size_t)m * 1024 + n] = acc[i][j][r];
            }
}

// ============================================================================
// Flash attention (R10 structure, unchanged): QBLK=128, 8 waves, swapped QK^T,
// exp2 softmax, defer-max, cvt_pk P-pack, K/V dbuf via global_load_lds.
// ============================================================================
__global__ __launch_bounds__(512) void attn_kernel(
    const unsigned short* __restrict__ Qb, const unsigned short* __restrict__ Kb,
    const unsigned short* __restrict__ Vtg, const float* __restrict__ rel_bias,
    unsigned short* __restrict__ A3) {
    const int qt = blockIdx.x;  // 0..7 (128 q-rows each)
    const int bh = blockIdx.y;  // 0..63
    const int b = bh >> 4, h = bh & 15;
    const int tid = threadIdx.x;
    const int w = tid >> 6, lane = tid & 63;  // w in 0..7
    const int lrow = lane & 15, lgrp = lane >> 4;
    const float LOG2E = 1.4426950408889634f;
    const float SCALE2 = 0.125f * 1.4426950408889634f;
    const float THR = 11.5f;  // ~8 nats in exp2 units

    __shared__ unsigned short Ks[2][64 * 64];  // 16 KB
    __shared__ unsigned short Vs[2][64 * 64];  // 16 KB
    __shared__ unsigned short Ps[8][16 * 64];  // 16 KB
    __shared__ float Bias2[2][192];

    const unsigned short* Ktile = Kb + (size_t)bh * 1024 * 64;
    const unsigned short* Vtile = Vtg + (size_t)bh * 64 * 1024;

    const unsigned short* Qp =
        Qb + ((size_t)bh * 1024 + qt * 128 + w * 16 + lrow) * 64;
    bf16x8 qa0 = *reinterpret_cast<const bf16x8*>(Qp + lgrp * 8);
    bf16x8 qa1 = *reinterpret_cast<const bf16x8*>(Qp + 32 + lgrp * 8);

    const int sr0 = w * 8 + (lane >> 3);
    const int sc_lo = lane & 7;

    float m_run = -3.0e38f;
    float l_run = 0.f;
    f32x4 o_acc[4];
#pragma unroll
    for (int n = 0; n < 4; n++) {
        f32x4 z = {0.f, 0.f, 0.f, 0.f};
        o_acc[n] = z;
    }

    const int bbase = lgrp * 4 + 127 - w * 16 - lrow;

    {
        {
            int r = sr0;
            int c = sc_lo ^ (r & 7);
            __builtin_amdgcn_global_load_lds(
                (const gbl_t*)(Ktile + (size_t)r * 64 + c * 8),
                (lds_t*)(&Ks[0][0] + w * 512), 16, 0, 0);
            __builtin_amdgcn_global_load_lds(
                (const gbl_t*)(Vtile + (size_t)r * 1024 + c * 8),
                (lds_t*)(&Vs[0][0] + w * 512), 16, 0, 0);
        }
        if (tid < 192) {
            int rowi = 0 - qt * 128 + 896 + tid;
            rowi = (rowi < 2046) ? rowi : 2046;
            Bias2[0][tid] = rel_bias[(size_t)rowi * 16 + h] * LOG2E;
        }
        asm volatile("s_waitcnt vmcnt(0)" ::: "memory");
        __syncthreads();
    }

    for (int kv = 0; kv < 16; ++kv) {
        const int cur = kv & 1;
        if (kv < 15) {
            const int j0n = (kv + 1) * 64;
            int r = sr0;
            int c = sc_lo ^ (r & 7);
            __builtin_amdgcn_global_load_lds(
                (const gbl_t*)(Ktile + (size_t)(j0n + r) * 64 + c * 8),
                (lds_t*)(&Ks[cur ^ 1][0] + w * 512), 16, 0, 0);
            __builtin_amdgcn_global_load_lds(
                (const gbl_t*)(Vtile + (size_t)r * 1024 + j0n + c * 8),
                (lds_t*)(&Vs[cur ^ 1][0] + w * 512), 16, 0, 0);
            if (tid < 192) {
                int rowi = j0n - qt * 128 + 896 + tid;
                rowi = (rowi < 2046) ? rowi : 2046;
                Bias2[cur ^ 1][tid] = rel_bias[(size_t)rowi * 16 + h] * LOG2E;
            }
        }

        const unsigned short* kbuf = &Ks[cur][0];
        f32x4 s[4];
        __builtin_amdgcn_s_setprio(1);
#pragma unroll
        for (int f = 0; f < 4; ++f) {
            int krow = f * 16 + lrow;
            int sw0 = (lgrp ^ (lrow & 7)) * 8;
            int sw1 = ((4 | lgrp) ^ (lrow & 7)) * 8;
            bf16x8 kb0 = *reinterpret_cast<const bf16x8*>(kbuf + krow * 64 + sw0);
            bf16x8 kb1 = *reinterpret_cast<const bf16x8*>(kbuf + krow * 64 + sw1);
            f32x4 z = {0.f, 0.f, 0.f, 0.f};
            z = MFMA16(kb0, qa0, z);
            z = MFMA16(kb1, qa1, z);
            s[f] = z;
        }
        __builtin_amdgcn_s_setprio(0);

        float x[4][4];
        float pm = -3.0e38f;
#pragma unroll
        for (int f = 0; f < 4; ++f)
#pragma unroll
            for (int r = 0; r < 4; ++r) {
                float xv = s[f][r] * SCALE2 + Bias2[cur][bbase + f * 16 + r];
                x[f][r] = xv;
                pm = fmaxf(pm, xv);
            }
        pm = fmaxf(pm, __shfl_xor(pm, 16));
        pm = fmaxf(pm, __shfl_xor(pm, 32));

        if (!__all(pm - m_run <= THR)) {
            float mnew = fmaxf(m_run, pm);
            float corr = __builtin_amdgcn_exp2f(m_run - mnew);
            m_run = mnew;
            l_run *= corr;
            float cb[4];
#pragma unroll
            for (int r = 0; r < 4; ++r) cb[r] = __shfl(corr, lgrp * 4 + r);
#pragma unroll
            for (int n = 0; n < 4; n++)
#pragma unroll
                for (int r = 0; r < 4; r++) o_acc[n][r] *= cb[r];
        }

        float su = 0.f;
#pragma unroll
        for (int f = 0; f < 4; ++f)
#pragma unroll
            for (int r = 0; r < 4; ++r) {
                float pv = __builtin_amdgcn_exp2f(x[f][r] - m_run);
                x[f][r] = pv;
                su += pv;
            }
        l_run += su;

#pragma unroll
        for (int f = 0; f < 4; ++f) {
            unsigned int plo, phi;
            asm("v_cvt_pk_bf16_f32 %0, %1, %2"
                : "=v"(plo)
                : "v"(x[f][0]), "v"(x[f][1]));
            asm("v_cvt_pk_bf16_f32 %0, %1, %2"
                : "=v"(phi)
                : "v"(x[f][2]), "v"(x[f][3]));
            const int chunk = (f * 2 + (lgrp >> 1)) ^ (lrow & 7);
            uint2 pw;
            pw.x = plo;
            pw.y = phi;
            *reinterpret_cast<uint2*>(
                &Ps[w][lrow * 64 + chunk * 8 + (lgrp & 1) * 4]) = pw;
        }

        const unsigned short* vbuf = &Vs[cur][0];
        __builtin_amdgcn_s_setprio(1);
#pragma unroll
        for (int jc = 0; jc < 2; ++jc) {
            int pc = ((4 * jc + lgrp) ^ (lrow & 7)) * 8;
            bf16x8 pa =
                *reinterpret_cast<const bf16x8*>(&Ps[w][0] + lrow * 64 + pc);
#pragma unroll
            for (int n = 0; n < 4; n++) {
                int vrow = n * 16 + lrow;
                bf16x8 vb =
                    *reinterpret_cast<const bf16x8*>(vbuf + vrow * 64 + pc);
                o_acc[n] = MFMA16(pa, vb, o_acc[n]);
            }
        }
        __builtin_amdgcn_s_setprio(0);

        if (kv < 15) {
            asm volatile("s_waitcnt vmcnt(0)" ::: "memory");
            __syncthreads();
        }
    }

    float lt = l_run + __shfl_xor(l_run, 16);
    lt += __shfl_xor(lt, 32);
    float rl[4];
#pragma unroll
    for (int r = 0; r < 4; ++r) rl[r] = 1.0f / __shfl(lt, lgrp * 4 + r);

    // compact hi-only epilogue
#pragma unroll
    for (int n = 0; n < 4; n++) {
#pragma unroll
        for (int r = 0; r < 4; r++) {
            float val = o_acc[n][r] * rl[r];
            int ia = qt * 128 + w * 16 + lgrp * 4 + r;
            size_t m = (size_t)b * 1024 + ia;
            int col = h * 64 + n * 16 + lrow;
            A3[m * 1024 + col] = f2bf(val);
        }
    }
}

extern "C" void kernel_launch(void* const* d_in, const int* in_sizes, int n_in,
                              void* d_out, int out_size, void* d_ws,
                              size_t ws_size, hipStream_t stream) {
    const float* x = (const float*)d_in[0];
    const float* w_qkv = (const float*)d_in[1];
    const float* w_out = (const float*)d_in[2];
    const float* rel_bias = (const float*)d_in[3];
    float* out = (float*)d_out;

    char* ws = (char*)d_ws;
    size_t off = 0;
    auto alloc = [&](size_t bytes) {
        char* p = ws + off;
        off += (bytes + 255) & ~(size_t)255;
        return p;
    };
    unsigned short* A1h = (unsigned short*)alloc((size_t)4096 * 1024 * 2);
    unsigned short* W1h = (unsigned short*)alloc((size_t)3072 * 1024 * 2);
    unsigned short* Qb = (unsigned short*)alloc((size_t)64 * 1024 * 64 * 2);
    unsigned short* Kb = (unsigned short*)alloc((size_t)64 * 1024 * 64 * 2);
    unsigned short* Vtg = (unsigned short*)alloc((size_t)64 * 64 * 1024 * 2);
    unsigned short* A3h = (unsigned short*)alloc((size_t)4096 * 1024 * 2);
    unsigned short* W3h = (unsigned short*)alloc((size_t)1024 * 1024 * 2);
    // NOTE: Vtg is a fresh buffer (no aliasing with A1h) — gemm256_hi writes
    // V^T while other blocks are still reading A1h.

    hipLaunchKernelGGL(prep_hi_rows, dim3(1024), dim3(256), 0, stream, x, A1h,
                       4096 * 256);
    hipLaunchKernelGGL(prep_hi_wqkv, dim3(768), dim3(256), 0, stream, w_qkv,
                       W1h);
    hipLaunchKernelGGL(prep_hi_rows, dim3(256), dim3(256), 0, stream, w_out,
                       W3h, 1024 * 256);
    hipLaunchKernelGGL(gemm256_hi, dim3(12, 32), dim3(512), 0, stream, A1h, W1h,
                       Qb, Kb, Vtg);
    hipLaunchKernelGGL(attn_kernel, dim3(8, 64), dim3(512), 0, stream, Qb, Kb,
                       Vtg, rel_bias, A3h);
    hipLaunchKernelGGL(gemm_out_v4, dim3(512), dim3(256), 0, stream, A3h, W3h,
                       out);
}